// Round 14
// baseline (167.707 us; speedup 1.0000x reference)
//
#include <hip/hip_runtime.h>

#define BN_S 0.9999950000374997f

constexpr int BATCH = 64;

typedef __attribute__((ext_vector_type(8))) short bf16x8;
typedef __attribute__((ext_vector_type(4))) float f32x4;

__device__ __forceinline__ float bnrelu(float x, float gs, float bb) {
    return fmaxf(fmaf(x, gs, bb), 0.f);
}

__device__ __forceinline__ unsigned short f2bf(float f) {
    unsigned u = __builtin_bit_cast(unsigned, f);
    return (unsigned short)((u + 0x7FFFu + ((u >> 16) & 1u)) >> 16);
}
__device__ __forceinline__ float bf2f(unsigned short h) {
    unsigned u = ((unsigned)h) << 16;
    return __builtin_bit_cast(float, u);
}

// ---------- generic fused conv3x3 tile (r11/r13 verbatim) ----------
template<int CIN, int CICH, int COUT, int CO_PER, int HIN, int WIN,
         int HOUT, int WOUT, int STRIDE, int ROWS, int P, int PARTS,
         bool PRE_BN, int SC, int CSC, int SSTR, int SCPARTS, bool WTL>
__device__ void convT_tile(float* smem, int band, int b, int zci,
    const float* __restrict__ in, size_t in_pstride,
    const float* __restrict__ w,
    const float* __restrict__ g, const float* __restrict__ bb,
    const float* __restrict__ xin, size_t xin_pstride,
    const float* __restrict__ g1v, const float* __restrict__ b1v,
    const float* __restrict__ wsc,
    float* __restrict__ out, size_t out_pstride)
{
    constexpr int IR = (STRIDE == 1) ? ROWS + 2 : 2 * ROWS + 1;
    constexpr int TW = (STRIDE == 1) ? WIN + 2 : WIN + 1;
    constexpr int AW = (P - 1) * STRIDE + 3;
    constexpr int PGW = WOUT / P;
    constexpr int NG = ROWS * PGW;
    constexpr int NITEMS = NG * (COUT / CO_PER);
    static_assert(NITEMS <= 256, "one item per thread");

    float* xs   = smem;
    float* wlds = xs + CICH * IR * TW;
    float* wscl = wlds + CICH * 9 * COUT;
    float* g1l  = wscl + ((SC == 2) ? CSC * COUT : 0);
    float* b1l  = g1l + (SC ? CSC : 0);

    const int ci0 = zci * CICH;
    const int r0 = band * ROWS;
    const int r0in = r0 * STRIDE - 1;
    const int tid = threadIdx.x;

    if constexpr (WTL) {
        const float* wsrc = w + (size_t)ci0 * 9 * COUT;
        for (int i = tid; i < CICH * 9 * COUT; i += 256) wlds[i] = wsrc[i];
    } else {
        for (int i = tid; i < CICH * 9 * COUT; i += 256) {
            int co = i % COUT; int rem = i / COUT; int tap = rem % 9; int ci = rem / 9;
            wlds[i] = w[((size_t)co * CIN + ci0 + ci) * 9 + tap];
        }
    }
    if constexpr (SC != 0) {
        if (tid < CSC) { g1l[tid] = g1v[tid] * BN_S; b1l[tid] = b1v[tid]; }
        if constexpr (SC == 2) {
            for (int i = tid; i < CSC * COUT; i += 256) {
                int co = i % COUT; int ci = i / COUT;
                wscl[i] = wsc[(size_t)co * CSC + ci];
            }
        }
    }
    for (int i = tid; i < CICH * IR * TW; i += 256) {
        int cc = i % TW; int rem = i / TW; int rr = rem % IR; int ci = rem / IR;
        int gr = r0in + rr; int gc = cc - 1;
        float v = 0.f;
        if (gr >= 0 && gr < HIN && gc >= 0 && gc < WIN) {
            size_t off = ((size_t)(b * CIN + ci0 + ci) * HIN + gr) * WIN + gc;
            v = in[off];
#pragma unroll
            for (int s = 1; s < PARTS; ++s) v += in[off + (size_t)s * in_pstride];
            if constexpr (PRE_BN) v = bnrelu(v, g[ci0 + ci] * BN_S, bb[ci0 + ci]);
        }
        xs[i] = v;
    }
    __syncthreads();

    if (tid < NITEMS) {
        const int it = tid;
        const int cog = it / NG; const int gi = it % NG;
        const int lr = gi / PGW; const int wc = (gi % PGW) * P;
        float acc[P][CO_PER];
#pragma unroll
        for (int j = 0; j < P; ++j)
#pragma unroll
            for (int co = 0; co < CO_PER; ++co) acc[j][co] = 0.f;

        for (int ci = 0; ci < CICH; ++ci) {
            const float* xb = xs + ((ci * IR) + lr * STRIDE) * TW + wc * STRIDE;
#pragma unroll
            for (int dh = 0; dh < 3; ++dh) {
                float aw[AW];
#pragma unroll
                for (int a = 0; a < AW; ++a) aw[a] = xb[dh * TW + a];
#pragma unroll
                for (int dw = 0; dw < 3; ++dw) {
                    const float* wp = wlds + (ci * 9 + dh * 3 + dw) * COUT + cog * CO_PER;
#pragma unroll
                    for (int c4 = 0; c4 < CO_PER; c4 += 4) {
                        float4 wv = *(const float4*)(wp + c4);
#pragma unroll
                        for (int j = 0; j < P; ++j) {
                            float a_ = aw[j * STRIDE + dw];
                            acc[j][c4 + 0] = fmaf(a_, wv.x, acc[j][c4 + 0]);
                            acc[j][c4 + 1] = fmaf(a_, wv.y, acc[j][c4 + 1]);
                            acc[j][c4 + 2] = fmaf(a_, wv.z, acc[j][c4 + 2]);
                            acc[j][c4 + 3] = fmaf(a_, wv.w, acc[j][c4 + 3]);
                        }
                    }
                }
            }
        }

        if constexpr (SC == 1) {
            if (zci == 0) {
#pragma unroll
                for (int co = 0; co < CO_PER; ++co) {
                    int c = cog * CO_PER + co;
#pragma unroll
                    for (int j = 0; j < P; ++j) {
                        size_t off = ((size_t)(b * CSC + c) * HOUT + (r0 + lr)) * WOUT + wc + j;
                        float v = xin[off];
#pragma unroll
                        for (int s = 1; s < SCPARTS; ++s) v += xin[off + s * xin_pstride];
                        acc[j][co] += bnrelu(v, g1l[c], b1l[c]);
                    }
                }
            }
        }
        if constexpr (SC == 2) {
            if (zci == 0) {
                const int hix = (r0 + lr) * SSTR;
                for (int ci = 0; ci < CSC; ++ci) {
                    float vv[P];
#pragma unroll
                    for (int j = 0; j < P; ++j) {
                        size_t off = ((size_t)(b * CSC + ci) * (HOUT * SSTR) + hix) * (WOUT * SSTR)
                                     + (wc + j) * SSTR;
                        float v = xin[off];
#pragma unroll
                        for (int s = 1; s < SCPARTS; ++s) v += xin[off + s * xin_pstride];
                        vv[j] = bnrelu(v, g1l[ci], b1l[ci]);
                    }
                    const float* wp = wscl + ci * COUT + cog * CO_PER;
#pragma unroll
                    for (int c4 = 0; c4 < CO_PER; c4 += 4) {
                        float4 wv = *(const float4*)(wp + c4);
#pragma unroll
                        for (int j = 0; j < P; ++j) {
                            acc[j][c4 + 0] = fmaf(vv[j], wv.x, acc[j][c4 + 0]);
                            acc[j][c4 + 1] = fmaf(vv[j], wv.y, acc[j][c4 + 1]);
                            acc[j][c4 + 2] = fmaf(vv[j], wv.z, acc[j][c4 + 2]);
                            acc[j][c4 + 3] = fmaf(vv[j], wv.w, acc[j][c4 + 3]);
                        }
                    }
                }
            }
        }

        float* op = out + (size_t)zci * out_pstride
                    + ((size_t)(b * COUT + cog * CO_PER) * HOUT + (r0 + lr)) * WOUT + wc;
#pragma unroll
        for (int co = 0; co < CO_PER; ++co)
#pragma unroll
            for (int j = 0; j < P; ++j)
                op[(size_t)co * HOUT * WOUT + j] = acc[j][co];
    }
}

template<int CIN, int CICH, int COUT, int CO_PER, int HIN, int WIN,
         int HOUT, int WOUT, int STRIDE, int ROWS, int P, int PARTS,
         bool PRE_BN, int SC, int CSC, int SSTR, int SCPARTS, bool WTL>
__global__ __launch_bounds__(256) void convT_k(
    const float* __restrict__ in, size_t in_pstride,
    const float* __restrict__ w,
    const float* __restrict__ g, const float* __restrict__ bb,
    const float* __restrict__ xin, size_t xin_pstride,
    const float* __restrict__ g1v, const float* __restrict__ b1v,
    const float* __restrict__ wsc,
    float* __restrict__ out, size_t out_pstride)
{
    constexpr int IR = (STRIDE == 1) ? ROWS + 2 : 2 * ROWS + 1;
    constexpr int TW = (STRIDE == 1) ? WIN + 2 : WIN + 1;
    constexpr int SM = CICH * IR * TW + CICH * 9 * COUT
                     + ((SC == 2) ? CSC * COUT : 0) + (SC ? 2 * CSC : 0);
    __shared__ __align__(16) float smem[SM];
    convT_tile<CIN, CICH, COUT, CO_PER, HIN, WIN, HOUT, WOUT, STRIDE, ROWS, P,
               PARTS, PRE_BN, SC, CSC, SSTR, SCPARTS, WTL>(
        smem, blockIdx.x, blockIdx.y, blockIdx.z,
        in, in_pstride, w, g, bb, xin, xin_pstride, g1v, b1v, wsc, out, out_pstride);
}

// ---------- prep: wfrag (768) + stem conv (384) + weight transpose (288) --
__global__ __launch_bounds__(256) void prep_k(
    const float* __restrict__ ctw, short* __restrict__ wf,
    const float* __restrict__ x, const float* __restrict__ conv_w,
    float* __restrict__ h0,
    const float* __restrict__ s1w1, const float* __restrict__ s1w2,
    const float* __restrict__ s2w1, const float* __restrict__ s2w2,
    const float* __restrict__ s3w1, const float* __restrict__ s3w2,
    float* __restrict__ wt)
{
    __shared__ __align__(16) float smem[3 * 8 * 62 + 3 * 9 * 16];
    int tl = blockIdx.x;
    if (tl < 768) {
        int id = tl * 256 + threadIdx.x;   // < 196608
        int j = id & 7; int lane = (id >> 3) & 63; int t4 = (id >> 9) & 3; int s = id >> 11;
        int c, ch;
        if (s < 32) { c = s; ch = 0; }
        else { c = 32 + ((s - 32) >> 1); ch = (s - 32) & 1; }
        int k = ch * 32 + ((lane >> 4) << 3) + j;
        int o = t4 * 16 + (lane & 15);
        float val = 0.f;
        if (k <= c) val = ctw[o * 2080 + (k * (129 - k)) / 2 + (c - k)];
        wf[id] = (short)f2bf(val);
    } else if (tl < 1152) {
        int tt = tl - 768;   // < 384
        convT_tile<3, 3, 16, 8, 36, 60, 36, 60, 1, 6, 3, 1, false, 0, 1, 1, 1, false>(
            smem, tt % 6, tt / 6, 0, x, 0, conv_w, nullptr, nullptr,
            nullptr, 0, nullptr, nullptr, nullptr, h0, 0);
    } else {
        // transpose conv weights into [ci][tap][co] linear blobs
        int id = (tl - 1152) * 256 + threadIdx.x;   // < 73728
        int base, CIN_, COUT_;
        const float* src;
        if (id < 2304)       { base = 0;     CIN_ = 16; COUT_ = 16; src = s1w1; }
        else if (id < 4608)  { base = 2304;  CIN_ = 16; COUT_ = 16; src = s1w2; }
        else if (id < 9216)  { base = 4608;  CIN_ = 16; COUT_ = 32; src = s2w1; }
        else if (id < 18432) { base = 9216;  CIN_ = 32; COUT_ = 32; src = s2w2; }
        else if (id < 36864) { base = 18432; CIN_ = 32; COUT_ = 64; src = s3w1; }
        else                 { base = 36864; CIN_ = 64; COUT_ = 64; src = s3w2; }
        int n = id - base;
        int co = n % COUT_; int tap = (n / COUT_) % 9; int ci = n / (9 * COUT_);
        wt[id] = src[((size_t)co * CIN_ + ci) * 9 + tap];
    }
}

// ---------- reduce b3c2 -> xp: grid (64, 4cq, 3 pixel-chunks), 8 partials --
__global__ __launch_bounds__(256) void red_k(
    const float* __restrict__ pb, const float* __restrict__ h2,
    const float* __restrict__ g1, const float* __restrict__ b1,
    const float* __restrict__ wsc, const float* __restrict__ bng,
    const float* __restrict__ bnb, float* __restrict__ xp)
{
    __shared__ float hsc[32][46];
    __shared__ float wscl[32][16];
    __shared__ float g1l[32], b1l[32];
    const int b = blockIdx.x, cq = blockIdx.y, pc = blockIdx.z;
    const int c0 = cq * 16;
    const int pbase = pc * 45;
    const int t = threadIdx.x;

    if (t < 32) { g1l[t] = g1[t] * BN_S; b1l[t] = b1[t]; }
    for (int i = t; i < 512; i += 256) {
        int ci = i & 31, cc = i >> 5;
        wscl[ci][cc] = wsc[(size_t)(c0 + cc) * 32 + ci];
    }
    __syncthreads();
    for (int i = t; i < 32 * 45; i += 256) {
        int ci = i / 45, pl = i % 45;
        int p = pbase + pl;
        int hp = p / 15, wp = p % 15;
        size_t off = ((size_t)(b * 32 + ci) * 18 + hp * 2) * 30 + wp * 2;
        float v = h2[off] + h2[off + 1105920] + h2[off + 2 * 1105920] + h2[off + 3 * 1105920];
        hsc[ci][pl] = bnrelu(v, g1l[ci], b1l[ci]);
    }
    __syncthreads();

    for (int e = t; e < 16 * 45; e += 256) {
        int cc = e / 45, pl = e % 45;
        int p = pbase + pl;
        int c = c0 + cc;
        size_t idx = ((size_t)(b * 64 + c)) * 135 + p;
        float y = 0.f;
#pragma unroll
        for (int q = 0; q < 8; ++q) y += pb[idx + (size_t)q * 552960];
#pragma unroll 8
        for (int ci = 0; ci < 32; ++ci) y = fmaf(hsc[ci][pl], wscl[ci][cc], y);
        xp[((size_t)b * 135 + p) * 64 + c] = bnrelu(y, bng[c] * BN_S, bnb[c]);
    }
}

// ---------- MFMA bilinear-pooling GEMM: 64 pixels/block, grid (135,4) -----
template<int NCH>
__device__ void f2m_body(
    const unsigned short* xs, int q, const short* __restrict__ wf,
    const float* __restrict__ ctb, float* __restrict__ Abase, int p0, int t)
{
    float* A = Abase + (size_t)q * 552960;
    const int w = t >> 6, lane = t & 63;
    const int prow = w * 16;
    const int lrow = lane & 15, lk = lane >> 4;

    bf16x8 Af[NCH];
#pragma unroll
    for (int ch = 0; ch < NCH; ++ch) {
        int pix = prow + lrow;
        int g = ch * 4 + lk;
        Af[ch] = *(const bf16x8*)&xs[pix * 64 + ((g ^ (pix & 7)) * 8)];
    }

    f32x4 acc[4];
#pragma unroll
    for (int tt = 0; tt < 4; ++tt) acc[tt] = f32x4{0.f, 0.f, 0.f, 0.f};

    const int c0 = q * 16;
    bf16x8 BA[NCH][4], BB[NCH][4];

    auto loadB = [&](int c, bf16x8 (&B)[NCH][4]) {
        int slotb = (NCH == 1) ? c : (2 * c - 32);
#pragma unroll
        for (int ch = 0; ch < NCH; ++ch) {
            const short* wb = wf + (size_t)(slotb + ch) * 2048 + lane * 8;
#pragma unroll
            for (int tt = 0; tt < 4; ++tt)
                B[ch][tt] = *(const bf16x8*)(wb + tt * 512);
        }
    };
    auto compute = [&](int c, bf16x8 (&B)[NCH][4]) {
        f32x4 S[4];
#pragma unroll
        for (int tt = 0; tt < 4; ++tt) S[tt] = f32x4{0.f, 0.f, 0.f, 0.f};
#pragma unroll
        for (int ch = 0; ch < NCH; ++ch)
#pragma unroll
            for (int tt = 0; tt < 4; ++tt)
                S[tt] = __builtin_amdgcn_mfma_f32_16x16x32_bf16(Af[ch], B[ch][tt], S[tt], 0, 0, 0);
#pragma unroll
        for (int j = 0; j < 4; ++j) {
            int pix = prow + lk * 4 + j;
            float sv = bf2f(xs[pix * 64 + (((c >> 3) ^ (pix & 7)) * 8) + (c & 7)]);
#pragma unroll
            for (int tt = 0; tt < 4; ++tt)
                acc[tt][j] += sv * S[tt][j];
        }
    };

    loadB(c0, BA);
#pragma unroll 1
    for (int ci = 0; ci < 16; ci += 2) {
        loadB(c0 + ci + 1, BB);
        compute(c0 + ci, BA);
        if (ci < 14) loadB(c0 + ci + 2, BA);
        compute(c0 + ci + 1, BB);
    }

#pragma unroll
    for (int j = 0; j < 4; ++j) {
        int gpix = p0 + prow + lk * 4 + j;   // < 8640 (135*64 grid)
#pragma unroll
        for (int tt = 0; tt < 4; ++tt) {
            int o = tt * 16 + lrow;
            float vv = acc[tt][j];
            if (q == 0) vv += ctb[o];
            A[(size_t)gpix * 64 + o] = vv;
        }
    }
}

__global__ __launch_bounds__(256) void f2m_k(
    const float* __restrict__ xp, const short* __restrict__ wf,
    const float* __restrict__ ctb, float* __restrict__ Abase)
{
    __shared__ unsigned short xs[64 * 64];
    const int t = threadIdx.x;
    const int p0 = blockIdx.x * 64;
    const int q = blockIdx.y;

    {   // stage 64 rows of xp as bf16, 16B-group XOR-swizzled by (pix&7)
        int pr = t >> 2, seg = t & 3;
        const float4* src = (const float4*)(xp + (size_t)(p0 + pr) * 64 + seg * 16);
        float v[16];
#pragma unroll
        for (int i = 0; i < 4; ++i) {
            float4 x4 = src[i];
            v[i*4+0] = x4.x; v[i*4+1] = x4.y; v[i*4+2] = x4.z; v[i*4+3] = x4.w;
        }
#pragma unroll
        for (int gi = 0; gi < 2; ++gi) {
            unsigned w0 = f2bf(v[gi*8+0]) | ((unsigned)f2bf(v[gi*8+1]) << 16);
            unsigned w1 = f2bf(v[gi*8+2]) | ((unsigned)f2bf(v[gi*8+3]) << 16);
            unsigned w2 = f2bf(v[gi*8+4]) | ((unsigned)f2bf(v[gi*8+5]) << 16);
            unsigned w3 = f2bf(v[gi*8+6]) | ((unsigned)f2bf(v[gi*8+7]) << 16);
            int grp = seg * 2 + gi;
            int sg = grp ^ (pr & 7);
            *(uint4*)&xs[pr * 64 + sg * 8] = make_uint4(w0, w1, w2, w3);
        }
    }
    __syncthreads();

    if (q < 2) f2m_body<1>(xs, q, wf, ctb, Abase, p0, t);
    else       f2m_body<2>(xs, q, wf, ctb, Abase, p0, t);
}

// ---------- fused gating: grid (64 images, 5 chunks); G in LDS ----------
__global__ __launch_bounds__(256) void f3_k(
    const float* __restrict__ xp, const float* __restrict__ A,
    float* __restrict__ out)
{
    __shared__ float red[256];
    __shared__ float gG[64];
    const int b = blockIdx.x, cz = blockIdx.y;
    const int t = threadIdx.x;
    const int o = t & 63, grp = t >> 6;

    float s = 0.f;
    for (int p = grp; p < 135; p += 4) {
        size_t off = ((size_t)b * 135 + p) * 64 + o;
        s += A[off] + A[off + 552960] + A[off + 2 * 552960] + A[off + 3 * 552960];
    }
    red[grp * 64 + o] = s;
    __syncthreads();
    if (t < 64)
        gG[t] = (red[t] + red[64 + t] + red[128 + t] + red[192 + t]) * (1.0f / 135.0f);
    __syncthreads();

    const size_t base = (size_t)b * 8640;
    for (int e = cz * 1728 + t; e < (cz + 1) * 1728; e += 256) {
        size_t idx = base + e;
        int oo = e & 63;
        float a = A[idx] + A[idx + 552960] + A[idx + 2 * 552960] + A[idx + 3 * 552960];
        float x = xp[idx];
        out[idx] = fmaf(x, a * (gG[oo] + 1.f), x);
    }
}

extern "C" void kernel_launch(void* const* d_in, const int* in_sizes, int n_in,
                              void* d_out, int out_size, void* d_ws, size_t ws_size,
                              hipStream_t stream)
{
    const float* x      = (const float*)d_in[0];
    const float* conv_w = (const float*)d_in[2];
    const float* s1_g1  = (const float*)d_in[3];
    const float* s1_b1  = (const float*)d_in[4];
    const float* s1_w1  = (const float*)d_in[5];
    const float* s1_g2  = (const float*)d_in[6];
    const float* s1_b2  = (const float*)d_in[7];
    const float* s1_w2  = (const float*)d_in[8];
    const float* s2_g1  = (const float*)d_in[9];
    const float* s2_b1  = (const float*)d_in[10];
    const float* s2_w1  = (const float*)d_in[11];
    const float* s2_g2  = (const float*)d_in[12];
    const float* s2_b2  = (const float*)d_in[13];
    const float* s2_w2  = (const float*)d_in[14];
    const float* s2_ws  = (const float*)d_in[15];
    const float* s3_g1  = (const float*)d_in[16];
    const float* s3_b1  = (const float*)d_in[17];
    const float* s3_w1  = (const float*)d_in[18];
    const float* s3_g2  = (const float*)d_in[19];
    const float* s3_b2  = (const float*)d_in[20];
    const float* s3_w2  = (const float*)d_in[21];
    const float* s3_ws  = (const float*)d_in[22];
    const float* bn_g   = (const float*)d_in[23];
    const float* bn_b   = (const float*)d_in[24];
    const float* ct_w   = (const float*)d_in[25];
    const float* ct_b   = (const float*)d_in[26];
    float* out = (float*)d_out;

    float* ws = (float*)d_ws;
    // flat, non-overlapping workspace (floats) — r11/r13 layout:
    float* h0      = ws + 0;          // [0, 2211840)
    float* p_b1c1  = ws + 2211840;    // 2x [2211840, 6635520)
    float* p_h1    = ws + 6635520;    // 2x [6635520, 11059200)
    float* p_b2c1  = ws + 11059200;   // 2x [11059200, 13271040)
    float* p_b2c2  = ws + 13271040;   // 4x [13271040, 17694720)
    float* p_b3c1  = ws + 17694720;   // 4x [17694720, 19906560)
    float* p_b3c2  = ws + 19906560;   // 8x [19906560, 24330240)
    float* xp      = ws + 24330240;   // [24330240, 24883200)
    float* A       = ws + 24883200;   // 4x [24883200, 27095040)
    short* wfrag   = (short*)(ws + 27095040);  // 196608 bf16 -> 98304 floats
    float* wt      = ws + 27193344;   // 73728 [27193344, 27267072)

    dim3 blk(256);

    // K1: wfrag (768) + stem conv (384) + weight transpose (288)
    prep_k<<<1440, blk, 0, stream>>>(ct_w, wfrag, x, conv_w, h0,
                                     s1_w1, s1_w2, s2_w1, s2_w2, s3_w1, s3_w2, wt);

    // K2: b1c1 16->16, ROWS=4 P=4 (NITEMS 240) CO_PER=4 CICH=8 z=2 -> 1152 blocks
    convT_k<16, 8, 16, 4, 36, 60, 36, 60, 1, 4, 4, 1, true, 0, 1, 1, 1, true>
        <<<dim3(9, 64, 2), blk, 0, stream>>>(
        h0, 0, wt + 0, s1_g1, s1_b1, nullptr, 0, nullptr, nullptr, nullptr,
        p_b1c1, 2211840);
    // K3: b1c2 sum2 -> conv + identity sc(h0), P=4, CICH=8 z=2 -> 1152 blocks
    convT_k<16, 8, 16, 4, 36, 60, 36, 60, 1, 4, 4, 2, true, 1, 16, 1, 1, true>
        <<<dim3(9, 64, 2), blk, 0, stream>>>(
        p_b1c1, 2211840, wt + 2304, s1_g2, s1_b2, h0, 0, s1_g1, s1_b1, nullptr,
        p_h1, 2211840);
    // K4: b2c1 16->32 s2, sum2(h1), CICH=8 z=2 -> 768 blocks
    convT_k<16, 8, 32, 4, 36, 60, 18, 30, 2, 3, 3, 2, true, 0, 1, 1, 1, true>
        <<<dim3(6, 64, 2), blk, 0, stream>>>(
        p_h1, 2211840, wt + 4608, s2_g1, s2_b1, nullptr, 0, nullptr, nullptr, nullptr,
        p_b2c1, 1105920);
    // K5: b2c2 32->32 sum2, CICH=8 z=4 + 1x1 sc(h1 sum2) -> 1536 blocks
    convT_k<32, 8, 32, 4, 18, 30, 18, 30, 1, 3, 3, 2, true, 2, 16, 2, 2, true>
        <<<dim3(6, 64, 4), blk, 0, stream>>>(
        p_b2c1, 1105920, wt + 9216, s2_g2, s2_b2, p_h1, 2211840, s2_g1, s2_b1, s2_ws,
        p_b2c2, 1105920);
    // K6: b3c1 32->64 s2, sum4, CICH=8 z=4 -> 768 blocks
    convT_k<32, 8, 64, 4, 18, 30, 9, 15, 2, 3, 3, 4, true, 0, 1, 1, 1, true>
        <<<dim3(3, 64, 4), blk, 0, stream>>>(
        p_b2c2, 1105920, wt + 18432, s3_g1, s3_b1, nullptr, 0, nullptr, nullptr, nullptr,
        p_b3c1, 552960);
    // K7: b3c2 64->64, sum4, CICH=8 z=8 -> 1536 blocks
    convT_k<64, 8, 64, 4, 9, 15, 9, 15, 1, 3, 3, 4, true, 0, 1, 1, 1, true>
        <<<dim3(3, 64, 8), blk, 0, stream>>>(
        p_b3c1, 552960, wt + 36864, s3_g2, s3_b2, nullptr, 0, nullptr, nullptr, nullptr,
        p_b3c2, 552960);
    // K8: reduce (8 conv partials + 1x1 sc(sum4 h2) + final bn) -> xp, 768 blocks
    red_k<<<dim3(64, 4, 3), blk, 0, stream>>>(p_b3c2, p_b2c2,
                                              s3_g1, s3_b1, s3_ws, bn_g, bn_b, xp);
    // K9: MFMA pooling GEMM, 540 blocks
    f2m_k<<<dim3(135, 4), blk, 0, stream>>>(xp, wfrag, ct_b, A);
    // K10: fused gating (G per image in LDS, 5 chunks wide) -> out
    f3_k<<<dim3(64, 5), blk, 0, stream>>>(xp, A, out);
}

// Round 15
// 164.848 us; speedup vs baseline: 1.0173x; 1.0173x over previous
//
#include <hip/hip_runtime.h>

#define BN_S 0.9999950000374997f

constexpr int BATCH = 64;

typedef __attribute__((ext_vector_type(8))) short bf16x8;
typedef __attribute__((ext_vector_type(4))) float f32x4;

__device__ __forceinline__ float bnrelu(float x, float gs, float bb) {
    return fmaxf(fmaf(x, gs, bb), 0.f);
}

__device__ __forceinline__ unsigned short f2bf(float f) {
    unsigned u = __builtin_bit_cast(unsigned, f);
    return (unsigned short)((u + 0x7FFFu + ((u >> 16) & 1u)) >> 16);
}
__device__ __forceinline__ float bf2f(unsigned short h) {
    unsigned u = ((unsigned)h) << 16;
    return __builtin_bit_cast(float, u);
}

// ---------- generic fused conv3x3 tile (r13 verbatim) ----------
template<int CIN, int CICH, int COUT, int CO_PER, int HIN, int WIN,
         int HOUT, int WOUT, int STRIDE, int ROWS, int P, int PARTS,
         bool PRE_BN, int SC, int CSC, int SSTR, int SCPARTS, bool WTL>
__device__ void convT_tile(float* smem, int band, int b, int zci,
    const float* __restrict__ in, size_t in_pstride,
    const float* __restrict__ w,
    const float* __restrict__ g, const float* __restrict__ bb,
    const float* __restrict__ xin, size_t xin_pstride,
    const float* __restrict__ g1v, const float* __restrict__ b1v,
    const float* __restrict__ wsc,
    float* __restrict__ out, size_t out_pstride)
{
    constexpr int IR = (STRIDE == 1) ? ROWS + 2 : 2 * ROWS + 1;
    constexpr int TW = (STRIDE == 1) ? WIN + 2 : WIN + 1;
    constexpr int AW = (P - 1) * STRIDE + 3;
    constexpr int PGW = WOUT / P;
    constexpr int NG = ROWS * PGW;
    constexpr int NITEMS = NG * (COUT / CO_PER);
    static_assert(NITEMS <= 256, "one item per thread");

    float* xs   = smem;
    float* wlds = xs + CICH * IR * TW;
    float* wscl = wlds + CICH * 9 * COUT;
    float* g1l  = wscl + ((SC == 2) ? CSC * COUT : 0);
    float* b1l  = g1l + (SC ? CSC : 0);

    const int ci0 = zci * CICH;
    const int r0 = band * ROWS;
    const int r0in = r0 * STRIDE - 1;
    const int tid = threadIdx.x;

    if constexpr (WTL) {
        const float* wsrc = w + (size_t)ci0 * 9 * COUT;
        for (int i = tid; i < CICH * 9 * COUT; i += 256) wlds[i] = wsrc[i];
    } else {
        for (int i = tid; i < CICH * 9 * COUT; i += 256) {
            int co = i % COUT; int rem = i / COUT; int tap = rem % 9; int ci = rem / 9;
            wlds[i] = w[((size_t)co * CIN + ci0 + ci) * 9 + tap];
        }
    }
    if constexpr (SC != 0) {
        if (tid < CSC) { g1l[tid] = g1v[tid] * BN_S; b1l[tid] = b1v[tid]; }
        if constexpr (SC == 2) {
            for (int i = tid; i < CSC * COUT; i += 256) {
                int co = i % COUT; int ci = i / COUT;
                wscl[i] = wsc[(size_t)co * CSC + ci];
            }
        }
    }
    for (int i = tid; i < CICH * IR * TW; i += 256) {
        int cc = i % TW; int rem = i / TW; int rr = rem % IR; int ci = rem / IR;
        int gr = r0in + rr; int gc = cc - 1;
        float v = 0.f;
        if (gr >= 0 && gr < HIN && gc >= 0 && gc < WIN) {
            size_t off = ((size_t)(b * CIN + ci0 + ci) * HIN + gr) * WIN + gc;
            v = in[off];
#pragma unroll
            for (int s = 1; s < PARTS; ++s) v += in[off + (size_t)s * in_pstride];
            if constexpr (PRE_BN) v = bnrelu(v, g[ci0 + ci] * BN_S, bb[ci0 + ci]);
        }
        xs[i] = v;
    }
    __syncthreads();

    if (tid < NITEMS) {
        const int it = tid;
        const int cog = it / NG; const int gi = it % NG;
        const int lr = gi / PGW; const int wc = (gi % PGW) * P;
        float acc[P][CO_PER];
#pragma unroll
        for (int j = 0; j < P; ++j)
#pragma unroll
            for (int co = 0; co < CO_PER; ++co) acc[j][co] = 0.f;

        for (int ci = 0; ci < CICH; ++ci) {
            const float* xb = xs + ((ci * IR) + lr * STRIDE) * TW + wc * STRIDE;
#pragma unroll
            for (int dh = 0; dh < 3; ++dh) {
                float aw[AW];
#pragma unroll
                for (int a = 0; a < AW; ++a) aw[a] = xb[dh * TW + a];
#pragma unroll
                for (int dw = 0; dw < 3; ++dw) {
                    const float* wp = wlds + (ci * 9 + dh * 3 + dw) * COUT + cog * CO_PER;
#pragma unroll
                    for (int c4 = 0; c4 < CO_PER; c4 += 4) {
                        float4 wv = *(const float4*)(wp + c4);
#pragma unroll
                        for (int j = 0; j < P; ++j) {
                            float a_ = aw[j * STRIDE + dw];
                            acc[j][c4 + 0] = fmaf(a_, wv.x, acc[j][c4 + 0]);
                            acc[j][c4 + 1] = fmaf(a_, wv.y, acc[j][c4 + 1]);
                            acc[j][c4 + 2] = fmaf(a_, wv.z, acc[j][c4 + 2]);
                            acc[j][c4 + 3] = fmaf(a_, wv.w, acc[j][c4 + 3]);
                        }
                    }
                }
            }
        }

        if constexpr (SC == 1) {
            if (zci == 0) {
#pragma unroll
                for (int co = 0; co < CO_PER; ++co) {
                    int c = cog * CO_PER + co;
#pragma unroll
                    for (int j = 0; j < P; ++j) {
                        size_t off = ((size_t)(b * CSC + c) * HOUT + (r0 + lr)) * WOUT + wc + j;
                        float v = xin[off];
#pragma unroll
                        for (int s = 1; s < SCPARTS; ++s) v += xin[off + s * xin_pstride];
                        acc[j][co] += bnrelu(v, g1l[c], b1l[c]);
                    }
                }
            }
        }
        if constexpr (SC == 2) {
            if (zci == 0) {
                const int hix = (r0 + lr) * SSTR;
                for (int ci = 0; ci < CSC; ++ci) {
                    float vv[P];
#pragma unroll
                    for (int j = 0; j < P; ++j) {
                        size_t off = ((size_t)(b * CSC + ci) * (HOUT * SSTR) + hix) * (WOUT * SSTR)
                                     + (wc + j) * SSTR;
                        float v = xin[off];
#pragma unroll
                        for (int s = 1; s < SCPARTS; ++s) v += xin[off + s * xin_pstride];
                        vv[j] = bnrelu(v, g1l[ci], b1l[ci]);
                    }
                    const float* wp = wscl + ci * COUT + cog * CO_PER;
#pragma unroll
                    for (int c4 = 0; c4 < CO_PER; c4 += 4) {
                        float4 wv = *(const float4*)(wp + c4);
#pragma unroll
                        for (int j = 0; j < P; ++j) {
                            acc[j][c4 + 0] = fmaf(vv[j], wv.x, acc[j][c4 + 0]);
                            acc[j][c4 + 1] = fmaf(vv[j], wv.y, acc[j][c4 + 1]);
                            acc[j][c4 + 2] = fmaf(vv[j], wv.z, acc[j][c4 + 2]);
                            acc[j][c4 + 3] = fmaf(vv[j], wv.w, acc[j][c4 + 3]);
                        }
                    }
                }
            }
        }

        float* op = out + (size_t)zci * out_pstride
                    + ((size_t)(b * COUT + cog * CO_PER) * HOUT + (r0 + lr)) * WOUT + wc;
#pragma unroll
        for (int co = 0; co < CO_PER; ++co)
#pragma unroll
            for (int j = 0; j < P; ++j)
                op[(size_t)co * HOUT * WOUT + j] = acc[j][co];
    }
}

template<int CIN, int CICH, int COUT, int CO_PER, int HIN, int WIN,
         int HOUT, int WOUT, int STRIDE, int ROWS, int P, int PARTS,
         bool PRE_BN, int SC, int CSC, int SSTR, int SCPARTS, bool WTL>
__global__ __launch_bounds__(256) void convT_k(
    const float* __restrict__ in, size_t in_pstride,
    const float* __restrict__ w,
    const float* __restrict__ g, const float* __restrict__ bb,
    const float* __restrict__ xin, size_t xin_pstride,
    const float* __restrict__ g1v, const float* __restrict__ b1v,
    const float* __restrict__ wsc,
    float* __restrict__ out, size_t out_pstride)
{
    constexpr int IR = (STRIDE == 1) ? ROWS + 2 : 2 * ROWS + 1;
    constexpr int TW = (STRIDE == 1) ? WIN + 2 : WIN + 1;
    constexpr int SM = CICH * IR * TW + CICH * 9 * COUT
                     + ((SC == 2) ? CSC * COUT : 0) + (SC ? 2 * CSC : 0);
    __shared__ __align__(16) float smem[SM];
    convT_tile<CIN, CICH, COUT, CO_PER, HIN, WIN, HOUT, WOUT, STRIDE, ROWS, P,
               PARTS, PRE_BN, SC, CSC, SSTR, SCPARTS, WTL>(
        smem, blockIdx.x, blockIdx.y, blockIdx.z,
        in, in_pstride, w, g, bb, xin, xin_pstride, g1v, b1v, wsc, out, out_pstride);
}

// ---------- prep: wfrag (768) + stem conv (384) + weight transpose (288) --
__global__ __launch_bounds__(256) void prep_k(
    const float* __restrict__ ctw, short* __restrict__ wf,
    const float* __restrict__ x, const float* __restrict__ conv_w,
    float* __restrict__ h0,
    const float* __restrict__ s1w1, const float* __restrict__ s1w2,
    const float* __restrict__ s2w1, const float* __restrict__ s2w2,
    const float* __restrict__ s3w1, const float* __restrict__ s3w2,
    float* __restrict__ wt)
{
    __shared__ __align__(16) float smem[3 * 8 * 62 + 3 * 9 * 16];
    int tl = blockIdx.x;
    if (tl < 768) {
        int id = tl * 256 + threadIdx.x;   // < 196608
        int j = id & 7; int lane = (id >> 3) & 63; int t4 = (id >> 9) & 3; int s = id >> 11;
        int c, ch;
        if (s < 32) { c = s; ch = 0; }
        else { c = 32 + ((s - 32) >> 1); ch = (s - 32) & 1; }
        int k = ch * 32 + ((lane >> 4) << 3) + j;
        int o = t4 * 16 + (lane & 15);
        float val = 0.f;
        if (k <= c) val = ctw[o * 2080 + (k * (129 - k)) / 2 + (c - k)];
        wf[id] = (short)f2bf(val);
    } else if (tl < 1152) {
        int tt = tl - 768;   // < 384
        convT_tile<3, 3, 16, 8, 36, 60, 36, 60, 1, 6, 3, 1, false, 0, 1, 1, 1, false>(
            smem, tt % 6, tt / 6, 0, x, 0, conv_w, nullptr, nullptr,
            nullptr, 0, nullptr, nullptr, nullptr, h0, 0);
    } else {
        // transpose conv weights into [ci][tap][co] linear blobs
        int id = (tl - 1152) * 256 + threadIdx.x;   // < 73728
        int base, CIN_, COUT_;
        const float* src;
        if (id < 2304)       { base = 0;     CIN_ = 16; COUT_ = 16; src = s1w1; }
        else if (id < 4608)  { base = 2304;  CIN_ = 16; COUT_ = 16; src = s1w2; }
        else if (id < 9216)  { base = 4608;  CIN_ = 16; COUT_ = 32; src = s2w1; }
        else if (id < 18432) { base = 9216;  CIN_ = 32; COUT_ = 32; src = s2w2; }
        else if (id < 36864) { base = 18432; CIN_ = 32; COUT_ = 64; src = s3w1; }
        else                 { base = 36864; CIN_ = 64; COUT_ = 64; src = s3w2; }
        int n = id - base;
        int co = n % COUT_; int tap = (n / COUT_) % 9; int ci = n / (9 * COUT_);
        wt[id] = src[((size_t)co * CIN_ + ci) * 9 + tap];
    }
}

// ---------- reduce b3c2 -> xp: grid (64, 4cq, 3 pixel-chunks), 8 partials --
__global__ __launch_bounds__(256) void red_k(
    const float* __restrict__ pb, const float* __restrict__ h2,
    const float* __restrict__ g1, const float* __restrict__ b1,
    const float* __restrict__ wsc, const float* __restrict__ bng,
    const float* __restrict__ bnb, float* __restrict__ xp)
{
    __shared__ float hsc[32][46];
    __shared__ float wscl[32][16];
    __shared__ float g1l[32], b1l[32];
    const int b = blockIdx.x, cq = blockIdx.y, pc = blockIdx.z;
    const int c0 = cq * 16;
    const int pbase = pc * 45;
    const int t = threadIdx.x;

    if (t < 32) { g1l[t] = g1[t] * BN_S; b1l[t] = b1[t]; }
    for (int i = t; i < 512; i += 256) {
        int ci = i & 31, cc = i >> 5;
        wscl[ci][cc] = wsc[(size_t)(c0 + cc) * 32 + ci];
    }
    __syncthreads();
    for (int i = t; i < 32 * 45; i += 256) {
        int ci = i / 45, pl = i % 45;
        int p = pbase + pl;
        int hp = p / 15, wp = p % 15;
        size_t off = ((size_t)(b * 32 + ci) * 18 + hp * 2) * 30 + wp * 2;
        float v = h2[off] + h2[off + 1105920] + h2[off + 2 * 1105920] + h2[off + 3 * 1105920];
        hsc[ci][pl] = bnrelu(v, g1l[ci], b1l[ci]);
    }
    __syncthreads();

    for (int e = t; e < 16 * 45; e += 256) {
        int cc = e / 45, pl = e % 45;
        int p = pbase + pl;
        int c = c0 + cc;
        size_t idx = ((size_t)(b * 64 + c)) * 135 + p;
        float y = 0.f;
#pragma unroll
        for (int q = 0; q < 8; ++q) y += pb[idx + (size_t)q * 552960];
#pragma unroll 8
        for (int ci = 0; ci < 32; ++ci) y = fmaf(hsc[ci][pl], wscl[ci][cc], y);
        xp[((size_t)b * 135 + p) * 64 + c] = bnrelu(y, bng[c] * BN_S, bnb[c]);
    }
}

// ---------- MFMA bilinear-pooling GEMM: 64 pixels/block, grid (135,4) -----
template<int NCH>
__device__ void f2m_body(
    const unsigned short* xs, int q, const short* __restrict__ wf,
    const float* __restrict__ ctb, float* __restrict__ Abase, int p0, int t)
{
    float* A = Abase + (size_t)q * 552960;
    const int w = t >> 6, lane = t & 63;
    const int prow = w * 16;
    const int lrow = lane & 15, lk = lane >> 4;

    bf16x8 Af[NCH];
#pragma unroll
    for (int ch = 0; ch < NCH; ++ch) {
        int pix = prow + lrow;
        int g = ch * 4 + lk;
        Af[ch] = *(const bf16x8*)&xs[pix * 64 + ((g ^ (pix & 7)) * 8)];
    }

    f32x4 acc[4];
#pragma unroll
    for (int tt = 0; tt < 4; ++tt) acc[tt] = f32x4{0.f, 0.f, 0.f, 0.f};

    const int c0 = q * 16;
    bf16x8 BA[NCH][4], BB[NCH][4];

    auto loadB = [&](int c, bf16x8 (&B)[NCH][4]) {
        int slotb = (NCH == 1) ? c : (2 * c - 32);
#pragma unroll
        for (int ch = 0; ch < NCH; ++ch) {
            const short* wb = wf + (size_t)(slotb + ch) * 2048 + lane * 8;
#pragma unroll
            for (int tt = 0; tt < 4; ++tt)
                B[ch][tt] = *(const bf16x8*)(wb + tt * 512);
        }
    };
    auto compute = [&](int c, bf16x8 (&B)[NCH][4]) {
        f32x4 S[4];
#pragma unroll
        for (int tt = 0; tt < 4; ++tt) S[tt] = f32x4{0.f, 0.f, 0.f, 0.f};
#pragma unroll
        for (int ch = 0; ch < NCH; ++ch)
#pragma unroll
            for (int tt = 0; tt < 4; ++tt)
                S[tt] = __builtin_amdgcn_mfma_f32_16x16x32_bf16(Af[ch], B[ch][tt], S[tt], 0, 0, 0);
#pragma unroll
        for (int j = 0; j < 4; ++j) {
            int pix = prow + lk * 4 + j;
            float sv = bf2f(xs[pix * 64 + (((c >> 3) ^ (pix & 7)) * 8) + (c & 7)]);
#pragma unroll
            for (int tt = 0; tt < 4; ++tt)
                acc[tt][j] += sv * S[tt][j];
        }
    };

    loadB(c0, BA);
#pragma unroll 1
    for (int ci = 0; ci < 16; ci += 2) {
        loadB(c0 + ci + 1, BB);
        compute(c0 + ci, BA);
        if (ci < 14) loadB(c0 + ci + 2, BA);
        compute(c0 + ci + 1, BB);
    }

#pragma unroll
    for (int j = 0; j < 4; ++j) {
        int gpix = p0 + prow + lk * 4 + j;   // < 8640 (135*64 grid)
#pragma unroll
        for (int tt = 0; tt < 4; ++tt) {
            int o = tt * 16 + lrow;
            float vv = acc[tt][j];
            if (q == 0) vv += ctb[o];
            A[(size_t)gpix * 64 + o] = vv;
        }
    }
}

__global__ __launch_bounds__(256) void f2m_k(
    const float* __restrict__ xp, const short* __restrict__ wf,
    const float* __restrict__ ctb, float* __restrict__ Abase)
{
    __shared__ unsigned short xs[64 * 64];
    const int t = threadIdx.x;
    const int p0 = blockIdx.x * 64;
    const int q = blockIdx.y;

    {   // stage 64 rows of xp as bf16, 16B-group XOR-swizzled by (pix&7)
        int pr = t >> 2, seg = t & 3;
        const float4* src = (const float4*)(xp + (size_t)(p0 + pr) * 64 + seg * 16);
        float v[16];
#pragma unroll
        for (int i = 0; i < 4; ++i) {
            float4 x4 = src[i];
            v[i*4+0] = x4.x; v[i*4+1] = x4.y; v[i*4+2] = x4.z; v[i*4+3] = x4.w;
        }
#pragma unroll
        for (int gi = 0; gi < 2; ++gi) {
            unsigned w0 = f2bf(v[gi*8+0]) | ((unsigned)f2bf(v[gi*8+1]) << 16);
            unsigned w1 = f2bf(v[gi*8+2]) | ((unsigned)f2bf(v[gi*8+3]) << 16);
            unsigned w2 = f2bf(v[gi*8+4]) | ((unsigned)f2bf(v[gi*8+5]) << 16);
            unsigned w3 = f2bf(v[gi*8+6]) | ((unsigned)f2bf(v[gi*8+7]) << 16);
            int grp = seg * 2 + gi;
            int sg = grp ^ (pr & 7);
            *(uint4*)&xs[pr * 64 + sg * 8] = make_uint4(w0, w1, w2, w3);
        }
    }
    __syncthreads();

    if (q < 2) f2m_body<1>(xs, q, wf, ctb, Abase, p0, t);
    else       f2m_body<2>(xs, q, wf, ctb, Abase, p0, t);
}

// ---------- fused gating: grid (64 images, 5 chunks); G in LDS ----------
__global__ __launch_bounds__(256) void f3_k(
    const float* __restrict__ xp, const float* __restrict__ A,
    float* __restrict__ out)
{
    __shared__ float red[256];
    __shared__ float gG[64];
    const int b = blockIdx.x, cz = blockIdx.y;
    const int t = threadIdx.x;
    const int o = t & 63, grp = t >> 6;

    float s = 0.f;
    for (int p = grp; p < 135; p += 4) {
        size_t off = ((size_t)b * 135 + p) * 64 + o;
        s += A[off] + A[off + 552960] + A[off + 2 * 552960] + A[off + 3 * 552960];
    }
    red[grp * 64 + o] = s;
    __syncthreads();
    if (t < 64)
        gG[t] = (red[t] + red[64 + t] + red[128 + t] + red[192 + t]) * (1.0f / 135.0f);
    __syncthreads();

    const size_t base = (size_t)b * 8640;
    for (int e = cz * 1728 + t; e < (cz + 1) * 1728; e += 256) {
        size_t idx = base + e;
        int oo = e & 63;
        float a = A[idx] + A[idx + 552960] + A[idx + 2 * 552960] + A[idx + 3 * 552960];
        float x = xp[idx];
        out[idx] = fmaf(x, a * (gG[oo] + 1.f), x);
    }
}

extern "C" void kernel_launch(void* const* d_in, const int* in_sizes, int n_in,
                              void* d_out, int out_size, void* d_ws, size_t ws_size,
                              hipStream_t stream)
{
    const float* x      = (const float*)d_in[0];
    const float* conv_w = (const float*)d_in[2];
    const float* s1_g1  = (const float*)d_in[3];
    const float* s1_b1  = (const float*)d_in[4];
    const float* s1_w1  = (const float*)d_in[5];
    const float* s1_g2  = (const float*)d_in[6];
    const float* s1_b2  = (const float*)d_in[7];
    const float* s1_w2  = (const float*)d_in[8];
    const float* s2_g1  = (const float*)d_in[9];
    const float* s2_b1  = (const float*)d_in[10];
    const float* s2_w1  = (const float*)d_in[11];
    const float* s2_g2  = (const float*)d_in[12];
    const float* s2_b2  = (const float*)d_in[13];
    const float* s2_w2  = (const float*)d_in[14];
    const float* s2_ws  = (const float*)d_in[15];
    const float* s3_g1  = (const float*)d_in[16];
    const float* s3_b1  = (const float*)d_in[17];
    const float* s3_w1  = (const float*)d_in[18];
    const float* s3_g2  = (const float*)d_in[19];
    const float* s3_b2  = (const float*)d_in[20];
    const float* s3_w2  = (const float*)d_in[21];
    const float* s3_ws  = (const float*)d_in[22];
    const float* bn_g   = (const float*)d_in[23];
    const float* bn_b   = (const float*)d_in[24];
    const float* ct_w   = (const float*)d_in[25];
    const float* ct_b   = (const float*)d_in[26];
    float* out = (float*)d_out;

    float* ws = (float*)d_ws;
    // flat, non-overlapping workspace (floats) — r11/r13 layout:
    float* h0      = ws + 0;          // [0, 2211840)
    float* p_b1c1  = ws + 2211840;    // 2x [2211840, 6635520)
    float* p_h1    = ws + 6635520;    // 2x [6635520, 11059200)
    float* p_b2c1  = ws + 11059200;   // 2x [11059200, 13271040)
    float* p_b2c2  = ws + 13271040;   // 4x [13271040, 17694720)
    float* p_b3c1  = ws + 17694720;   // 4x [17694720, 19906560)
    float* p_b3c2  = ws + 19906560;   // 8x [19906560, 24330240)
    float* xp      = ws + 24330240;   // [24330240, 24883200)
    float* A       = ws + 24883200;   // 4x [24883200, 27095040)
    short* wfrag   = (short*)(ws + 27095040);  // 196608 bf16 -> 98304 floats
    float* wt      = ws + 27193344;   // 73728 [27193344, 27267072)

    dim3 blk(256);

    // K1: wfrag (768) + stem conv (384) + weight transpose (288)
    prep_k<<<1440, blk, 0, stream>>>(ct_w, wfrag, x, conv_w, h0,
                                     s1_w1, s1_w2, s2_w1, s2_w2, s3_w1, s3_w2, wt);

    // K2: b1c1 16->16, ROWS=4 P=5 CO_PER=4 CICH=8 z=2 -> 1152 blocks
    convT_k<16, 8, 16, 4, 36, 60, 36, 60, 1, 4, 5, 1, true, 0, 1, 1, 1, true>
        <<<dim3(9, 64, 2), blk, 0, stream>>>(
        h0, 0, wt + 0, s1_g1, s1_b1, nullptr, 0, nullptr, nullptr, nullptr,
        p_b1c1, 2211840);
    // K3: b1c2 sum2 -> conv + identity sc(h0), CICH=8 z=2 -> 1152 blocks
    convT_k<16, 8, 16, 4, 36, 60, 36, 60, 1, 4, 5, 2, true, 1, 16, 1, 1, true>
        <<<dim3(9, 64, 2), blk, 0, stream>>>(
        p_b1c1, 2211840, wt + 2304, s1_g2, s1_b2, h0, 0, s1_g1, s1_b1, nullptr,
        p_h1, 2211840);
    // K4: b2c1 16->32 s2, sum2(h1), CICH=8 z=2 -> 768 blocks
    convT_k<16, 8, 32, 4, 36, 60, 18, 30, 2, 3, 3, 2, true, 0, 1, 1, 1, true>
        <<<dim3(6, 64, 2), blk, 0, stream>>>(
        p_h1, 2211840, wt + 4608, s2_g1, s2_b1, nullptr, 0, nullptr, nullptr, nullptr,
        p_b2c1, 1105920);
    // K5: b2c2 32->32 sum2, CICH=8 z=4 + 1x1 sc(h1 sum2) -> 1536 blocks
    convT_k<32, 8, 32, 4, 18, 30, 18, 30, 1, 3, 3, 2, true, 2, 16, 2, 2, true>
        <<<dim3(6, 64, 4), blk, 0, stream>>>(
        p_b2c1, 1105920, wt + 9216, s2_g2, s2_b2, p_h1, 2211840, s2_g1, s2_b1, s2_ws,
        p_b2c2, 1105920);
    // K6: b3c1 32->64 s2, sum4, CICH=8 z=4 -> 768 blocks
    convT_k<32, 8, 64, 4, 18, 30, 9, 15, 2, 3, 3, 4, true, 0, 1, 1, 1, true>
        <<<dim3(3, 64, 4), blk, 0, stream>>>(
        p_b2c2, 1105920, wt + 18432, s3_g1, s3_b1, nullptr, 0, nullptr, nullptr, nullptr,
        p_b3c1, 552960);
    // K7: b3c2 64->64, sum4, CICH=8 z=8 -> 1536 blocks
    convT_k<64, 8, 64, 4, 9, 15, 9, 15, 1, 3, 3, 4, true, 0, 1, 1, 1, true>
        <<<dim3(3, 64, 8), blk, 0, stream>>>(
        p_b3c1, 552960, wt + 36864, s3_g2, s3_b2, nullptr, 0, nullptr, nullptr, nullptr,
        p_b3c2, 552960);
    // K8: reduce (8 conv partials + 1x1 sc(sum4 h2) + final bn) -> xp, 768 blocks
    red_k<<<dim3(64, 4, 3), blk, 0, stream>>>(p_b3c2, p_b2c2,
                                              s3_g1, s3_b1, s3_ws, bn_g, bn_b, xp);
    // K9: MFMA pooling GEMM, 540 blocks
    f2m_k<<<dim3(135, 4), blk, 0, stream>>>(xp, wfrag, ct_b, A);
    // K10: fused gating (G per image in LDS, 5 chunks wide) -> out
    f3_k<<<dim3(64, 5), blk, 0, stream>>>(xp, A, out);
}